// Round 5
// baseline (261.395 us; speedup 1.0000x reference)
//
#include <hip/hip_runtime.h>

#define TPB 512
#define EPT 8                 // elements per thread (2 x int4), consecutive -> stable order
#define EPB (TPB * EPT)       // 4096 elements per block
#define NE 8                  // experts
#define NWAVE (TPB / 64)      // 8 waves

typedef unsigned long long u64;
typedef unsigned int u32;
typedef int   v4i __attribute__((ext_vector_type(4)));
typedef float v4f __attribute__((ext_vector_type(4)));

// ---------------- Pass 1: histogram (expert-major) + 4-bit packed key stream ----------------
__global__ __launch_bounds__(TPB) void k_hist(const int* __restrict__ idx, int M,
                                              int* __restrict__ bh, int nblocks,
                                              u32* __restrict__ kpk) {
    const int b = blockIdx.x;
    const long gbase = (long)b * EPB + threadIdx.x * EPT;

    // packed counters: lo = bins 0-3 (4 x 16b), hi = bins 4-7
    u64 lo = 0, hi = 0;
    u32 kp = 0;
    if (gbase + EPT <= M) {
        v4i v0 = __builtin_nontemporal_load((const v4i*)(idx + gbase));
        v4i v1 = __builtin_nontemporal_load((const v4i*)(idx + gbase + 4));
        int e[8] = {v0.x, v0.y, v0.z, v0.w, v1.x, v1.y, v1.z, v1.w};
        #pragma unroll
        for (int j = 0; j < 8; ++j) {
            kp |= ((u32)(e[j] & 7)) << (4 * j);
            u64 inc = 1ULL << ((e[j] & 3) * 16);
            if (e[j] < 4) lo += inc; else hi += inc;
        }
        __builtin_nontemporal_store(kp, kpk + (long)b * TPB + threadIdx.x);
    } else if (gbase < M) {
        for (int j = 0; j < EPT; ++j) {
            if (gbase + j < M) {
                int e = idx[gbase + j];
                kp |= ((u32)(e & 7)) << (4 * j);
                u64 inc = 1ULL << ((e & 3) * 16);
                if (e < 4) lo += inc; else hi += inc;
            }
        }
        kpk[(long)b * TPB + threadIdx.x] = kp;
    }

    // wave butterfly reduce (fields <= 64*8 = 512, fits 16b)
    const int lane = threadIdx.x & 63;
    const int wave = threadIdx.x >> 6;
    #pragma unroll
    for (int m = 1; m < 64; m <<= 1) {
        lo += __shfl_xor(lo, m);
        hi += __shfl_xor(hi, m);
    }
    __shared__ u64 wlo[NWAVE], whi[NWAVE];
    if (lane == 0) { wlo[wave] = lo; whi[wave] = hi; }
    __syncthreads();
    if (threadIdx.x < NE) {
        int e = threadIdx.x;
        int f = e & 3;
        int tot = 0;
        #pragma unroll
        for (int wv = 0; wv < NWAVE; ++wv) {
            u64 p = (e < 4) ? wlo[wv] : whi[wv];
            tot += (int)((p >> (f * 16)) & 0xFFFF);
        }
        bh[(long)e * nblocks + b] = tot;   // expert-major
    }
}

// ---------------- Pass 2: stable scatter; per-block bases computed in-kernel ----------------
// bh is only NE*nblocks ints (128 KB) — every block reduces it from L2 instead of a
// separate serialized single-block scan kernel.
__global__ __launch_bounds__(TPB) void k_scatter(const u32* __restrict__ kpk,
                                                 const float* __restrict__ scores,
                                                 int M,
                                                 const int* __restrict__ bh, int nblocks,
                                                 float* __restrict__ outS,
                                                 float* __restrict__ outT,
                                                 float* __restrict__ outC) {
    const int b = blockIdx.x;
    const int t = threadIdx.x;
    const int lane = t & 63;
    const int wave = t >> 6;
    const long gbase = (long)b * EPB + t * EPT;

    // ---- per-block scatter bases: wave e reduces bh row e over [0,b) and [0,nblocks) ----
    __shared__ int sOff[NE], sTot[NE];
    {
        const int* row = bh + (long)wave * nblocks;
        int pre = 0, tot = 0;
        const int n4 = nblocks >> 2;
        for (int i4 = lane; i4 < n4; i4 += 64) {
            v4i v = *(const v4i*)(row + 4 * i4);
            const int base = 4 * i4;
            const int s4 = v.x + v.y + v.z + v.w;
            tot += s4;
            if (base + 4 <= b) pre += s4;
            else if (base < b) {
                if (base + 0 < b) pre += v.x;
                if (base + 1 < b) pre += v.y;
                if (base + 2 < b) pre += v.z;
                if (base + 3 < b) pre += v.w;
            }
        }
        for (int i = (nblocks & ~3) + lane; i < nblocks; i += 64) {
            int v = row[i];
            tot += v;
            if (i < b) pre += v;
        }
        #pragma unroll
        for (int m = 1; m < 64; m <<= 1) {
            pre += __shfl_xor(pre, m);
            tot += __shfl_xor(tot, m);
        }
        if (lane == 0) { sOff[wave] = pre; sTot[wave] = tot; }
    }

    // ---- load this block's packed keys + scores (overlaps with the bh reduce above) ----
    int  e[EPT];
    float s[EPT];
    int  nval = 0;
    if (gbase + EPT <= M) {
        u32 kp = __builtin_nontemporal_load(kpk + (long)b * TPB + t);
        v4f s0 = __builtin_nontemporal_load((const v4f*)(scores + gbase));
        v4f s1 = __builtin_nontemporal_load((const v4f*)(scores + gbase + 4));
        #pragma unroll
        for (int j = 0; j < 8; ++j) e[j] = (int)((kp >> (4 * j)) & 7u);
        s[0]=s0.x; s[1]=s0.y; s[2]=s0.z; s[3]=s0.w;
        s[4]=s1.x; s[5]=s1.y; s[6]=s1.z; s[7]=s1.w;
        nval = EPT;
    } else if (gbase < M) {
        u32 kp = kpk[(long)b * TPB + t];
        for (int j = 0; j < EPT; ++j) {
            if (gbase + j < M) { e[j] = (int)((kp >> (4 * j)) & 7u); s[j] = scores[gbase + j]; ++nval; }
            else { e[j] = 0; s[j] = 0.f; }
        }
    } else {
        for (int j = 0; j < EPT; ++j) { e[j] = 0; s[j] = 0.f; }
    }

    __syncthreads();
    // fold expert-start into sOff; block 0 writes expert counts
    if (t < NE) {
        int es = 0;
        for (int k = 0; k < t; ++k) es += sTot[k];
        sOff[t] += es;
        if (b == 0) outC[t] = (float)sTot[t];
    }

    // packed per-thread counts (element order)
    u64 lo = 0, hi = 0;
    for (int j = 0; j < nval; ++j) {
        u64 inc = 1ULL << ((e[j] & 3) * 16);
        if (e[j] < 4) lo += inc; else hi += inc;
    }

    // block exclusive scan of packed counters (fields <= 4096, fits 16b)
    u64 il = lo, ih = hi;
    #pragma unroll
    for (int d = 1; d < 64; d <<= 1) {
        u64 pl = __shfl_up(il, (unsigned)d);
        u64 ph = __shfl_up(ih, (unsigned)d);
        if (lane >= d) { il += pl; ih += ph; }
    }
    __shared__ u64 wlo[NWAVE], whi[NWAVE];
    if (lane == 63) { wlo[wave] = il; whi[wave] = ih; }
    __syncthreads();
    u64 addl = 0, addh = 0;
    for (int wv = 0; wv < wave; ++wv) { addl += wlo[wv]; addh += whi[wv]; }
    u64 rl = il - lo + addl;   // running exclusive packed offsets
    u64 rh = ih - hi + addh;

    // block totals -> per-expert local bases
    u64 tl = 0, th = 0;
    #pragma unroll
    for (int wv = 0; wv < NWAVE; ++wv) { tl += wlo[wv]; th += whi[wv]; }
    int cnt[NE], lBase[NE];
    {
        #pragma unroll
        for (int k = 0; k < 4; ++k) cnt[k]     = (int)((tl >> (16 * k)) & 0xFFFF);
        #pragma unroll
        for (int k = 0; k < 4; ++k) cnt[4 + k] = (int)((th >> (16 * k)) & 0xFFFF);
        int runb = 0;
        #pragma unroll
        for (int k = 0; k < NE; ++k) { lBase[k] = runb; runb += cnt[k]; }
    }

    // stage into LDS in final (sorted) order
    __shared__ float lsS[EPB];
    __shared__ float lsT[EPB];
    for (int j = 0; j < nval; ++j) {
        const int ej = e[j];
        const int f  = ej & 3;
        const u64 inc = 1ULL << (f * 16);
        int off;
        if (ej < 4) { off = (int)((rl >> (f * 16)) & 0xFFFF); rl += inc; }
        else        { off = (int)((rh >> (f * 16)) & 0xFFFF); rh += inc; }
        const int p = lBase[ej] + off;
        lsS[p] = s[j];
        lsT[p] = (float)(int)((gbase + j) >> 1);   // order // TOP_K (TOP_K == 2)
    }
    __syncthreads();

    // coalesced copy out: per expert run, 16B-aligned float4 body + scalar head/tail
    #pragma unroll
    for (int k = 0; k < NE; ++k) {
        const int c  = cnt[k];
        const int g0 = sOff[k];
        const int l0 = lBase[k];
        const int head = min((4 - (g0 & 3)) & 3, c);
        const int rem  = c - head;
        const int nb   = (rem > 0) ? (rem >> 2) : 0;
        const int done = head + 4 * nb;
        const int tail = c - done;

        if (t < head) {
            __builtin_nontemporal_store(lsS[l0 + t], outS + g0 + t);
            __builtin_nontemporal_store(lsT[l0 + t], outT + g0 + t);
        }
        for (int j4 = t; j4 < nb; j4 += TPB) {
            const int i = head + 4 * j4;
            v4f vs = { lsS[l0+i], lsS[l0+i+1], lsS[l0+i+2], lsS[l0+i+3] };
            v4f vt = { lsT[l0+i], lsT[l0+i+1], lsT[l0+i+2], lsT[l0+i+3] };
            __builtin_nontemporal_store(vs, (v4f*)(outS + g0 + i));
            __builtin_nontemporal_store(vt, (v4f*)(outT + g0 + i));
        }
        if (t < tail) {
            __builtin_nontemporal_store(lsS[l0 + done + t], outS + g0 + done + t);
            __builtin_nontemporal_store(lsT[l0 + done + t], outT + g0 + done + t);
        }
    }
}

extern "C" void kernel_launch(void* const* d_in, const int* in_sizes, int n_in,
                              void* d_out, int out_size, void* d_ws, size_t ws_size,
                              hipStream_t stream) {
    const float* scores = (const float*)d_in[0];
    const int*   idx    = (const int*)d_in[1];
    const int M = in_sizes[1];                 // N_TOKENS * TOP_K flat keys

    float* out  = (float*)d_out;
    float* outS = out;                          // [0, M)   sorted scores
    float* outT = out + M;                      // [M, 2M)  token indices (as f32, exact < 2^24)
    float* outC = out + 2 * (long)M;            // [2M, 2M+8) expert counts

    const int nblocks = (M + EPB - 1) / EPB;    // 4096 for M = 16,777,216
    int* bh  = (int*)d_ws;                      // NE * nblocks ints, expert-major
    u32* kpk = (u32*)(bh + (long)NE * nblocks); // packed 4-bit keys, ceil(M/8) u32

    k_hist   <<<nblocks, TPB, 0, stream>>>(idx, M, bh, nblocks, kpk);
    k_scatter<<<nblocks, TPB, 0, stream>>>(kpk, scores, M, bh, nblocks, outS, outT, outC);
}